// Round 6
// baseline (35.383 us; speedup 1.0000x reference)
//
#include <hip/hip_runtime.h>
#include <math.h>
#include <stdint.h>

#define BATCH 32
#define ND 512
#define NC 100
#define JB 8
#define NJT 13          // j0 = 0,8,...,88, last tile j0=92 (overlap; max is idempotent)
#define NT 512
#define NW 8
#define BIGNEG 1000000.0f
#define PCOL 10         // floats per row in s_part (stride 10 words: 2-way banks, free)

__device__ __forceinline__ float rdlane_f(float v, int t) {
  return __uint_as_float(__builtin_amdgcn_readlane(__float_as_uint(v), (uint32_t)t));
}

__global__ __launch_bounds__(NT, 2) void adv_main(
    const float* __restrict__ z, const float* __restrict__ wu,
    const float* __restrict__ wl, const float* __restrict__ bu,
    const float* __restrict__ bl, const float* __restrict__ y,
    float* __restrict__ ws)
{
  // XCD-chunk swizzle: 416 = 8*52, bijective
  int id = (blockIdx.x & 7) * (NJT * BATCH / 8) + (blockIdx.x >> 3);
  const int b  = id / NJT;
  const int jt = id - b * NJT;
  const int j0 = (jt < NJT - 1) ? jt * JB : (NC - JB);

  const int tid = threadIdx.x;
  const int w   = tid >> 6;       // wave = n-group of 64
  const int l   = tid & 63;       // lane

  __shared__ float s_part[NW][128][PCOL];   // 40 KB partials
  __shared__ float s_lin[NW][JB];
  __shared__ float s_max[NW];

  // ---- staging: thread (w,l) owns n = w*64 + l ----
  const int ns = (w << 6) + l;
  const float* zb = z + b * 2 * ND;
  float zlo = zb[ns], zhi = zb[ND + ns];
  float c = 0.5f * (zlo + zhi);
  float r = 0.5f * (zhi - zlo);     // radius >= 0

  const float* wlr = wl + ((size_t)b * ND + ns) * NC + j0;   // j0 % 4 == 0 -> 16B aligned
  float4 qa = *(const float4*)wlr;
  float4 qb = *(const float4*)(wlr + 4);
  float vq[JB] = {qa.x, qa.y, qa.z, qa.w, qb.x, qb.y, qb.z, qb.w};

  // lin_l partial: L[jj] = sum_n c_n * wl[n][j0+jj] (per-wave, xor-reduce, one-time)
  {
    float p[JB];
#pragma unroll
    for (int jj = 0; jj < JB; ++jj) p[jj] = c * vq[jj];
#pragma unroll
    for (int off = 1; off < 64; off <<= 1) {
#pragma unroll
      for (int jj = 0; jj < JB; ++jj) p[jj] += __shfl_xor(p[jj], off, 64);
    }
    if (l == 0) {
#pragma unroll
      for (int jj = 0; jj < JB; ++jj) s_lin[w][jj] = p[jj];
    }
  }

  // ---- main loop: 64 n per wave, wl broadcast via v_readlane ----
  float acc0[JB] = {0,0,0,0,0,0,0,0};
  float acc1[JB] = {0,0,0,0,0,0,0,0};
  float ac0 = 0.f, ac1 = 0.f;

  const int i2 = (l + 64 < NC) ? (l + 64) : (NC - 1);   // clamp (OOB-safe), masked later
  const float* pA = wu + ((size_t)b * ND + (w << 6)) * NC + l;
  const float* pB = wu + ((size_t)b * ND + (w << 6)) * NC + i2;

#pragma unroll 4
  for (int t = 0; t < 64; ++t) {
    float w0 = pA[(size_t)t * NC];          // coalesced, L2-resident, vmcnt-pipelined
    float w1 = pB[(size_t)t * NC];
    float ct = rdlane_f(c, t);
    float rt = rdlane_f(r, t);
    ac0 = fmaf(ct, w0, ac0);
    ac1 = fmaf(ct, w1, ac1);
#pragma unroll
    for (int jj = 0; jj < JB; ++jj) {
      float q  = rdlane_f(vq[jj], t);
      float d0 = q - w0; acc0[jj] = fmaf(rt, fabsf(d0), acc0[jj]);
      float d1 = q - w1; acc1[jj] = fmaf(rt, fabsf(d1), acc1[jj]);
    }
  }

  // ---- dump per-wave partials to LDS ----
#pragma unroll
  for (int jj = 0; jj < JB; ++jj) s_part[w][l][jj] = acc0[jj];
  s_part[w][l][8] = ac0;
#pragma unroll
  for (int jj = 0; jj < JB; ++jj) s_part[w][64 + l][jj] = acc1[jj];
  s_part[w][64 + l][8] = ac1;
  __syncthreads();

  // ---- combine: thread -> (islot = tid>>2, j-pair = (tid&3)*2) ----
  const int islot = tid >> 2;          // 0..127 == i
  const int jj2   = (tid & 3) << 1;    // 0,2,4,6
  float s0 = 0.f, s1 = 0.f, aT = 0.f, L0 = 0.f, L1 = 0.f;
#pragma unroll
  for (int ww = 0; ww < NW; ++ww) {
    const float* pr = &s_part[ww][islot][0];
    s0 += pr[jj2]; s1 += pr[jj2 + 1]; aT += pr[8];
    L0 += s_lin[ww][jj2]; L1 += s_lin[ww][jj2 + 1];
  }

  float m = -INFINITY;
  if (islot < NC) {
    const int i = islot;
    float yi  = y[b * NC + i];
    float base = bu[b * NC + i] - BIGNEG * yi + aT;
    int j = j0 + jj2;
    float v0 = s0 + base - bl[b * NC + j]     - BIGNEG * (1.0f - y[b * NC + j])     - L0;
    float v1 = s1 + base - bl[b * NC + j + 1] - BIGNEG * (1.0f - y[b * NC + j + 1]) - L1;
    m = fmaxf(v0, v1);
  }

#pragma unroll
  for (int off = 32; off; off >>= 1) m = fmaxf(m, __shfl_down(m, off, 64));
  if (l == 0) s_max[w] = m;
  __syncthreads();
  if (tid == 0) {
    float rr = s_max[0];
#pragma unroll
    for (int ww = 1; ww < NW; ++ww) rr = fmaxf(rr, s_max[ww]);
    ws[b * NJT + jt] = rr;
  }
}

__global__ void adv_reduce(const float* __restrict__ ws, float* __restrict__ out) {
  int b = threadIdx.x;
  if (b < BATCH) {
    float m = -INFINITY;
#pragma unroll
    for (int jt = 0; jt < NJT; ++jt) m = fmaxf(m, ws[b * NJT + jt]);
    out[b] = m;
  }
}

extern "C" void kernel_launch(void* const* d_in, const int* in_sizes, int n_in,
                              void* d_out, int out_size, void* d_ws, size_t ws_size,
                              hipStream_t stream) {
  // inputs: 0:x (unused), 1:z_tensor, 2:w_u, 3:b_u, 4:w_l, 5:b_l, 6:y_tensor
  const float* z  = (const float*)d_in[1];
  const float* wu = (const float*)d_in[2];
  const float* bu = (const float*)d_in[3];
  const float* wl = (const float*)d_in[4];
  const float* bl = (const float*)d_in[5];
  const float* y  = (const float*)d_in[6];
  float* ws = (float*)d_ws;

  adv_main<<<NJT * BATCH, NT, 0, stream>>>(z, wu, wl, bu, bl, y, ws);
  adv_reduce<<<1, 64, 0, stream>>>(ws, (float*)d_out);
}